// Round 8
// baseline (100.333 us; speedup 1.0000x reference)
//
#include <hip/hip_runtime.h>

// NEUROPULS unitary mesh, N=256 — associative split (K=2) + tiled combine.
// R7 post-mortem: chain ~19us (as predicted), combine ~26us — each of 256
// blocks streamed all 512KB of Bbuf => 128MB aggregate cross-XCD dirty-L2
// traffic. Fix: 64-block 32x32-tiled combine (8MB aggregate) + chain uses
// the R6-validated fused operator F = MMI*P*MMI built IN-REGISTER off the
// serial chain (no shared table => no cross-XCD trap).

constexpr int N = 256;

__global__ __launch_bounds__(64)
void neuropuls_chain_kernel(const float* __restrict__ thetas,  // [130,256] fp32
                            float2* __restrict__ Abuf,         // [c][k] = A[k][c]
                            float2* __restrict__ Bbuf)         // [k][r] = B[r][k]
{
    const int lane = threadIdx.x;          // 0..63
    const bool isB = blockIdx.x >= 256;
    const int col  = blockIdx.x & 255;

    const float BT  = sqrtf(0.98f * 0.01f);            // CR a*sqrt(CT)
    const float BR  = sqrtf(0.98f * 0.99f);            // CR thru
    const float AT2 = 0.98f * 0.505f;                  // (a*t)^2
    const float AR2 = 0.98f * 0.495f;                  // (a*r)^2
    const float ATR = 0.98f * sqrtf(0.505f * 0.495f);  // a^2*t*r

    float vr[4] = {0.f, 0.f, 0.f, 0.f};
    float vi[4] = {0.f, 0.f, 0.f, 0.f};

    // start: chainA = diag(e^{i th0}) column; chainB = identity column
    {
        const int r0 = col - 4 * lane;
        if (0 <= r0 && r0 < 4) {
            if (isB) { vr[r0] = 1.f; }
            else {
                float s0, c0;
                __sincosf(thetas[col], &s0, &c0);
                vr[r0] = c0; vi[r0] = s0;
            }
        }
    }

    const int s0     = isB ? 65 : 1;
    const int nCross = isB ? 63 : 64;    // crossing stages: A 1..64, B 65..127
    const float* tp = thetas + s0 * N + 4 * lane;

    // fused 2x2 operator per even-pair j: {f00r,f00i,f01r,f01i,f11r,f11i}
    float F[2][6], G[2][6];

    auto buildF = [&](float4 th, float Fd[2][6]) {
        float sn[4], cs[4];
        __sincosf(th.x, &sn[0], &cs[0]);
        __sincosf(th.y, &sn[1], &cs[1]);
        __sincosf(th.z, &sn[2], &cs[2]);
        __sincosf(th.w, &sn[3], &cs[3]);
        #pragma unroll
        for (int j = 0; j < 2; ++j) {
            const int x = 2 * j, y = 2 * j + 1;
            Fd[j][0] = AT2 * cs[x] - AR2 * cs[y];
            Fd[j][1] = AT2 * sn[x] - AR2 * sn[y];
            Fd[j][2] = -ATR * (sn[x] + sn[y]);
            Fd[j][3] =  ATR * (cs[x] + cs[y]);
            Fd[j][4] = AT2 * cs[y] - AR2 * cs[x];
            Fd[j][5] = AT2 * sn[y] - AR2 * sn[x];
        }
    };
    auto applyF = [&](const float Fd[2][6]) {
        #pragma unroll
        for (int j = 0; j < 2; ++j) {
            const int x = 2 * j, y = 2 * j + 1;
            float z0r = vr[x], z0i = vi[x], z1r = vr[y], z1i = vi[y];
            vr[x] = Fd[j][0]*z0r - Fd[j][1]*z0i + Fd[j][2]*z1r - Fd[j][3]*z1i;
            vi[x] = Fd[j][0]*z0i + Fd[j][1]*z0r + Fd[j][2]*z1i + Fd[j][3]*z1r;
            vr[y] = Fd[j][2]*z0r - Fd[j][3]*z0i + Fd[j][4]*z1r - Fd[j][5]*z1i;
            vi[y] = Fd[j][2]*z0i + Fd[j][3]*z0r + Fd[j][4]*z1i + Fd[j][5]*z1r;
        }
    };
    auto crossing = [&]() {
        float pv3r = __shfl_up(vr[3], 1);
        float pv3i = __shfl_up(vi[3], 1);
        float nv0r = __shfl_down(vr[0], 1);
        float nv0i = __shfl_down(vi[0], 1);
        {   // internal odd pair (4t+1, 4t+2)
            float xr = vr[1], xi = vi[1], yr = vr[2], yi = vi[2];
            vr[1] = BT * xr - BR * yi;  vi[1] = BT * xi + BR * yr;
            vr[2] = BT * yr - BR * xi;  vi[2] = BT * yi + BR * xr;
        }
        {   // pair (4t-1, 4t): lane 0 row 0 = thru
            float yr = vr[0], yi = vi[0];
            float nr = BT * yr - BR * pv3i;
            float ni = BT * yi + BR * pv3r;
            vr[0] = (lane == 0) ? BR * yr : nr;
            vi[0] = (lane == 0) ? BR * yi : ni;
        }
        {   // pair (4t+3, 4t+4): lane 63 row 255 = thru
            float xr = vr[3], xi = vi[3];
            float nr = BT * xr - BR * nv0i;
            float ni = BT * xi + BR * nv0r;
            vr[3] = (lane == 63) ? BR * xr : nr;
            vi[3] = (lane == 63) ? BR * xi : ni;
        }
    };

    // pipeline: F = fused(theta[s]) ready; thN = theta[s+1] loaded
    float4 thN;
    {
        float4 t1 = *(const float4*)tp;  tp += N;
        thN = *(const float4*)tp;        tp += N;
        buildF(t1, F);
    }

    #pragma unroll 2
    for (int it = 0; it < nCross - 1; ++it) {
        float4 thNN = *(const float4*)tp;  tp += N;   // max read: theta[128] (B-half)
        buildF(thN, G);            // off the serial chain
        applyF(F);
        crossing();
        #pragma unroll
        for (int j = 0; j < 2; ++j)
            #pragma unroll
            for (int q = 0; q < 6; ++q) F[j][q] = G[j][q];
        thN = thNN;
    }

    // last crossing stage (A: s=64, B: s=127)
    applyF(F);
    crossing();

    if (isB) {
        // stage 128 (no crossing): thN == theta[128]
        buildF(thN, F);
        applyF(F);
        // final phase layer theta[129]
        float4 thF = *(const float4*)(thetas + 129 * N + 4 * lane);
        const float a[4] = {thF.x, thF.y, thF.z, thF.w};
        #pragma unroll
        for (int j = 0; j < 4; ++j) {
            float sn, cs;
            __sincosf(a[j], &sn, &cs);
            float r = vr[j], i = vi[j];
            vr[j] = cs * r - sn * i;
            vi[j] = cs * i + sn * r;
        }
    }

    float2* dst = (isB ? Bbuf : Abuf) + col * N + 4 * lane;
    #pragma unroll
    for (int j = 0; j < 4; ++j) dst[j] = make_float2(vr[j], vi[j]);
}

// out = B*A. 64 blocks: 8x8 grid of 32x32 tiles; k staged in LDS chunks of 64
// (k-major, pitch 34 float2 => float4-aligned rows, 2-way-bank-free reads).
__global__ __launch_bounds__(256)
void neuropuls_combine_kernel(const float2* __restrict__ Abuf,  // [c][k]
                              const float2* __restrict__ Bbuf,  // [k][r]
                              float* __restrict__ out)          // re[65536] || im[65536]
{
    constexpr int PITCH = 34;   // float2 per k-row (32 + 2 pad)
    constexpr int TK    = 64;   // k-chunk
    __shared__ float2 Al[TK * PITCH];   // Al[k][cl]  (17408 B)
    __shared__ float2 Bl[TK * PITCH];   // Bl[k][rl]

    const int t   = threadIdx.x;
    const int c0  = (blockIdx.x & 7) * 32;
    const int r0  = (blockIdx.x >> 3) * 32;
    const int cl2 = t & 15;     // col pair: c0 + 2*cl2 (+1)
    const int rq2 = t >> 4;     // row pair: r0 + 2*rq2 (+1)

    float ar00 = 0.f, ai00 = 0.f, ar01 = 0.f, ai01 = 0.f;
    float ar10 = 0.f, ai10 = 0.f, ar11 = 0.f, ai11 = 0.f;

    for (int kc = 0; kc < N; kc += TK) {
        // stage A chunk: Abuf[c0+cl][kc+k] -> Al[k][cl]; 1024 float4, 4/thread
        #pragma unroll
        for (int j = 0; j < 4; ++j) {
            int fl = t + j * 256;          // 0..1023
            int cl = fl >> 5;              // 0..31
            int k4 = fl & 31;              // float4 = k-pair within chunk
            float4 v = ((const float4*)(Abuf + (size_t)(c0 + cl) * N + kc))[k4];
            Al[(2 * k4    ) * PITCH + cl] = make_float2(v.x, v.y);
            Al[(2 * k4 + 1) * PITCH + cl] = make_float2(v.z, v.w);
        }
        // stage B chunk: Bbuf[kc+k][r0+rl] -> Bl[k][rl]
        #pragma unroll
        for (int j = 0; j < 4; ++j) {
            int fl  = t + j * 256;         // 0..1023
            int k   = fl >> 4;             // 0..63
            int rl4 = fl & 15;             // float4 = row-pair
            float4 v = ((const float4*)(Bbuf + (size_t)(kc + k) * N + r0))[rl4];
            Bl[k * PITCH + 2 * rl4]     = make_float2(v.x, v.y);
            Bl[k * PITCH + 2 * rl4 + 1] = make_float2(v.z, v.w);
        }
        __syncthreads();

        #pragma unroll 4
        for (int k = 0; k < TK; ++k) {
            float4 a = *(const float4*)&Al[k * PITCH + 2 * cl2];  // cols 2cl2,2cl2+1
            float4 b = *(const float4*)&Bl[k * PITCH + 2 * rq2];  // rows 2rq2,2rq2+1
            ar00 += b.x * a.x - b.y * a.y;  ai00 += b.x * a.y + b.y * a.x;
            ar01 += b.x * a.z - b.y * a.w;  ai01 += b.x * a.w + b.y * a.z;
            ar10 += b.z * a.x - b.w * a.y;  ai10 += b.z * a.y + b.w * a.x;
            ar11 += b.z * a.z - b.w * a.w;  ai11 += b.z * a.w + b.w * a.z;
        }
        __syncthreads();
    }

    const int r = r0 + 2 * rq2, c = c0 + 2 * cl2;
    out[r * N + c]                 = ar00;  out[N * N + r * N + c]           = ai00;
    out[r * N + c + 1]             = ar01;  out[N * N + r * N + c + 1]       = ai01;
    out[(r + 1) * N + c]           = ar10;  out[N * N + (r + 1) * N + c]     = ai10;
    out[(r + 1) * N + c + 1]       = ar11;  out[N * N + (r + 1) * N + c + 1] = ai11;
}

extern "C" void kernel_launch(void* const* d_in, const int* in_sizes, int n_in,
                              void* d_out, int out_size, void* d_ws, size_t ws_size,
                              hipStream_t stream)
{
    const float* thetas = (const float*)d_in[0];   // [130,256] fp32
    float2* Abuf = (float2*)d_ws;                  // 512 KB
    float2* Bbuf = Abuf + N * N;                   // 512 KB
    float* out = (float*)d_out;                    // planar: re[65536] || im[65536]
    (void)in_sizes; (void)n_in; (void)out_size; (void)ws_size;

    neuropuls_chain_kernel<<<dim3(512), dim3(64), 0, stream>>>(thetas, Abuf, Bbuf);
    neuropuls_combine_kernel<<<dim3(64), dim3(256), 0, stream>>>(Abuf, Bbuf, out);
}